// Round 15
// baseline (211.117 us; speedup 1.0000x reference)
//
#include <hip/hip_runtime.h>
#include <hip/hip_bf16.h>

// Problem constants
#define IN_DIM 128
#define HID    64
#define NFW    8256     // IN*HID + HID
#define BATCH  256
#define K2     16512    // 2*NFW
#define BM     64       // rows per m-block
#define NMB    129      // 8256/64
#define KSPLIT 4        // 129 BK128-supers = 33+32+32+32
#define GRID_M 516      // NMB*KSPLIT; 3 blocks/CU capacity -> single generation

typedef float f32x4 __attribute__((ext_vector_type(4)));
typedef float f32x2 __attribute__((ext_vector_type(2)));
typedef short bf16x8 __attribute__((ext_vector_type(8)));

__device__ __forceinline__ unsigned int f2bf(float f) {
    union { float f; unsigned int u; } v; v.f = f;
    return (v.u + 0x7FFFu + ((v.u >> 16) & 1u)) >> 16;   // RNE f32->bf16 (bits)
}

// ---------------------------------------------------------------------------
// Kernel 0: W1 (16512x128 f32) -> W1T tiled bf16. Tile kt: [128 n][64 kl].
// ---------------------------------------------------------------------------
__global__ __launch_bounds__(256) void k_prep_w1t(const float* __restrict__ W1,
                                                  unsigned short* __restrict__ W1T) {
    __shared__ float tile[64][IN_DIM + 1];
    const int kt = blockIdx.x;               // 0..257
    const int t  = threadIdx.x;
    const float* src = W1 + (size_t)kt * 64 * IN_DIM;
#pragma unroll
    for (int p = 0; p < 8; ++p) {
        int c4 = p * 256 + t;
        int e = c4 * 4;
        int row = e >> 7, col = e & 127;
        f32x4 v = *reinterpret_cast<const f32x4*>(src + row * IN_DIM + col);
        tile[row][col+0] = v.x; tile[row][col+1] = v.y;
        tile[row][col+2] = v.z; tile[row][col+3] = v.w;
    }
    __syncthreads();
    unsigned short* dst = W1T + (size_t)kt * (IN_DIM * 64);
#pragma unroll
    for (int it = 0; it < 4; ++it) {
        int c = it * 256 + t;
        int n = c >> 3, kl0 = (c & 7) * 8;
        uint4 w;
        w.x = f2bf(tile[kl0+0][n]) | (f2bf(tile[kl0+1][n]) << 16);
        w.y = f2bf(tile[kl0+2][n]) | (f2bf(tile[kl0+3][n]) << 16);
        w.z = f2bf(tile[kl0+4][n]) | (f2bf(tile[kl0+5][n]) << 16);
        w.w = f2bf(tile[kl0+6][n]) | (f2bf(tile[kl0+7][n]) << 16);
        *reinterpret_cast<uint4*>(dst + c * 8) = w;
    }
}

// ---------------------------------------------------------------------------
// Kernel 1: split-K GEMM with INSTRUCTION-CONTIGUOUS A loads.
// Super = BK128 (512B/row): wave-instruction l = global_load_dwordx2 where
// 64 lanes cover ONE row's 512B contiguously (vs 8 scattered 256B segments
// per instruction in R7-R14 — the one thing never varied across 7 neutral
// scheduling experiments). 16 named f32x2/thread; dribbled to LDS one BK64
// half per phase via half-wave-masked ds_write_b32 (final LDS layout ==
// proven swizzled format; frag reads unchanged). 48KB LDS + ~120 VGPR at
// (256,3) -> 3 blocks/CU -> grid 516 single-generation (no stragglers).
// B staging, LBAR (lgkmcnt-only), MFMA-first, XCD grouping, stagger kept.
// ---------------------------------------------------------------------------
__global__ __launch_bounds__(256, 3) void k_gemm_M(const float* __restrict__ W2,
                                                   const unsigned short* __restrict__ W1T,
                                                   float* __restrict__ Mpart) {
    __shared__ __align__(16) unsigned char smem[49152];  // A:2x8K @0, B:2x16K @16K
    float* trs = reinterpret_cast<float*>(smem);         // [32][132] epilogue alias

    const int t = threadIdx.x;
    const int lane = t & 63, wid = t >> 6;
    const int wm = wid >> 1, wn = wid & 1;    // wave grid 2m x 2n
    const int l15 = lane & 15, l4 = (lane >> 4) & 3;

    // bijective blockIdx -> (ks, mb); 516 = 4*65 + 4*64 across 8 XCDs
    // (2 XCDs per k-split -> B slice ~1MB stays L2-resident).
    const int b = blockIdx.x;
    const int xcd = b & 7, slot = b >> 3;
    const int p = (xcd < 4) ? (xcd * 65 + slot) : (260 + (xcd - 4) * 64 + slot);
    const int ks = p / NMB, mb = p % NMB;

    const int m0 = mb * BM;
    const int NS = (ks == 0) ? 33 : 32;       // supers in this split
    const int g0 = (ks == 0) ? 0 : (32 * ks + 1);
    const int st0 = (p * 7) % NS;             // stagger (fp32 acc: safe)

    // A staging: wave wid covers rows wid*16..+15; lane covers 8B at k=lane*2
    const float* abase = W2 + (size_t)(m0 + wid * 16) * K2 + lane * 2;
    // B staging: 2 threads per 128-B row; lane covers 64B (32 bf16)
    const int bn  = t >> 1;                   // row 0..127
    const int bsw = (bn & 7) << 4;
    const unsigned short* bbase = W1T + bn * 64 + (t & 1) * 32;

    // named staging regs
    f32x2 ra0, ra1, ra2, ra3, ra4, ra5, ra6, ra7;
    f32x2 ra8, ra9, ra10, ra11, ra12, ra13, ra14, ra15;
    uint4 sb0, sb1, sb2, sb3;
    f32x4 acc[2][4];
#pragma unroll
    for (int mf = 0; mf < 2; ++mf)
#pragma unroll
        for (int nf = 0; nf < 4; ++nf)
            acc[mf][nf] = (f32x4){0.f, 0.f, 0.f, 0.f};

#define LOADA(S) {                                                             \
    const float* _ap = abase + (size_t)(S) * 128;                              \
    ra0  = *reinterpret_cast<const f32x2*>(_ap);                               \
    ra1  = *reinterpret_cast<const f32x2*>(_ap + (size_t)1  * K2);             \
    ra2  = *reinterpret_cast<const f32x2*>(_ap + (size_t)2  * K2);             \
    ra3  = *reinterpret_cast<const f32x2*>(_ap + (size_t)3  * K2);             \
    ra4  = *reinterpret_cast<const f32x2*>(_ap + (size_t)4  * K2);             \
    ra5  = *reinterpret_cast<const f32x2*>(_ap + (size_t)5  * K2);             \
    ra6  = *reinterpret_cast<const f32x2*>(_ap + (size_t)6  * K2);             \
    ra7  = *reinterpret_cast<const f32x2*>(_ap + (size_t)7  * K2);             \
    ra8  = *reinterpret_cast<const f32x2*>(_ap + (size_t)8  * K2);             \
    ra9  = *reinterpret_cast<const f32x2*>(_ap + (size_t)9  * K2);             \
    ra10 = *reinterpret_cast<const f32x2*>(_ap + (size_t)10 * K2);             \
    ra11 = *reinterpret_cast<const f32x2*>(_ap + (size_t)11 * K2);             \
    ra12 = *reinterpret_cast<const f32x2*>(_ap + (size_t)12 * K2);             \
    ra13 = *reinterpret_cast<const f32x2*>(_ap + (size_t)13 * K2);             \
    ra14 = *reinterpret_cast<const f32x2*>(_ap + (size_t)14 * K2);             \
    ra15 = *reinterpret_cast<const f32x2*>(_ap + (size_t)15 * K2); }

#define LOADB(KT) {                                                            \
    const unsigned short* _bp = bbase + (size_t)(KT) * 8192;                   \
    sb0 = *reinterpret_cast<const uint4*>(_bp);                                \
    sb1 = *reinterpret_cast<const uint4*>(_bp + 8);                            \
    sb2 = *reinterpret_cast<const uint4*>(_bp + 16);                           \
    sb3 = *reinterpret_cast<const uint4*>(_bp + 24); }

// one row's 4B bf16-pair write; swizzle (L&7)<<4 is compile-time per L
#define STA1(BUF, L, RA) {                                                     \
    unsigned int _v = f2bf(RA.x) | (f2bf(RA.y) << 16);                         \
    *reinterpret_cast<unsigned int*>(&smem[(BUF) * 8192 +                      \
        (wid * 16 + (L)) * 128 + (((lane & 31) * 4) ^ (((L) & 7) << 4))]) = _v; }

#define STOREA_HALF(BUF, H) {                                                  \
    if ((lane >> 5) == (H)) {                                                  \
        STA1(BUF, 0,  ra0)  STA1(BUF, 1,  ra1)  STA1(BUF, 2,  ra2)             \
        STA1(BUF, 3,  ra3)  STA1(BUF, 4,  ra4)  STA1(BUF, 5,  ra5)             \
        STA1(BUF, 6,  ra6)  STA1(BUF, 7,  ra7)  STA1(BUF, 8,  ra8)             \
        STA1(BUF, 9,  ra9)  STA1(BUF, 10, ra10) STA1(BUF, 11, ra11)            \
        STA1(BUF, 12, ra12) STA1(BUF, 13, ra13) STA1(BUF, 14, ra14)            \
        STA1(BUF, 15, ra15)                                                    \
    } }

#define STOREB(BUF) {                                                          \
    unsigned char* _Bsh = smem + 16384 + (BUF) * 16384;                        \
    const int _bb = (t & 1) * 64;                                              \
    *reinterpret_cast<uint4*>(&_Bsh[bn * 128 + ((_bb)      ^ bsw)]) = sb0;     \
    *reinterpret_cast<uint4*>(&_Bsh[bn * 128 + ((_bb + 16) ^ bsw)]) = sb1;     \
    *reinterpret_cast<uint4*>(&_Bsh[bn * 128 + ((_bb + 32) ^ bsw)]) = sb2;     \
    *reinterpret_cast<uint4*>(&_Bsh[bn * 128 + ((_bb + 48) ^ bsw)]) = sb3; }

#define MFMA_PHASE(BUF) {                                                      \
    const unsigned char* _Ash = smem + (BUF) * 8192;                           \
    const unsigned char* _Bsh = smem + 16384 + (BUF) * 16384;                  \
    const int _fsw = (l15 & 7) << 4;                                           \
    _Pragma("unroll")                                                          \
    for (int kk = 0; kk < 2; ++kk) {                                           \
        const int _fc = (kk * 64 + l4 * 16) ^ _fsw;                            \
        bf16x8 af0 = *reinterpret_cast<const bf16x8*>(                         \
            &_Ash[(wm * 32 +  0 + l15) * 128 + _fc]);                          \
        bf16x8 af1 = *reinterpret_cast<const bf16x8*>(                         \
            &_Ash[(wm * 32 + 16 + l15) * 128 + _fc]);                          \
        bf16x8 bf0 = *reinterpret_cast<const bf16x8*>(                         \
            &_Bsh[(wn * 64 +  0 + l15) * 128 + _fc]);                          \
        bf16x8 bf1 = *reinterpret_cast<const bf16x8*>(                         \
            &_Bsh[(wn * 64 + 16 + l15) * 128 + _fc]);                          \
        bf16x8 bf2 = *reinterpret_cast<const bf16x8*>(                         \
            &_Bsh[(wn * 64 + 32 + l15) * 128 + _fc]);                          \
        bf16x8 bf3 = *reinterpret_cast<const bf16x8*>(                         \
            &_Bsh[(wn * 64 + 48 + l15) * 128 + _fc]);                          \
        acc[0][0] = __builtin_amdgcn_mfma_f32_16x16x32_bf16(af0, bf0, acc[0][0], 0, 0, 0); \
        acc[0][1] = __builtin_amdgcn_mfma_f32_16x16x32_bf16(af0, bf1, acc[0][1], 0, 0, 0); \
        acc[0][2] = __builtin_amdgcn_mfma_f32_16x16x32_bf16(af0, bf2, acc[0][2], 0, 0, 0); \
        acc[0][3] = __builtin_amdgcn_mfma_f32_16x16x32_bf16(af0, bf3, acc[0][3], 0, 0, 0); \
        acc[1][0] = __builtin_amdgcn_mfma_f32_16x16x32_bf16(af1, bf0, acc[1][0], 0, 0, 0); \
        acc[1][1] = __builtin_amdgcn_mfma_f32_16x16x32_bf16(af1, bf1, acc[1][1], 0, 0, 0); \
        acc[1][2] = __builtin_amdgcn_mfma_f32_16x16x32_bf16(af1, bf2, acc[1][2], 0, 0, 0); \
        acc[1][3] = __builtin_amdgcn_mfma_f32_16x16x32_bf16(af1, bf3, acc[1][3], 0, 0, 0); \
    } }

#define LBAR() { asm volatile("s_waitcnt lgkmcnt(0)" ::: "memory");            \
                 __builtin_amdgcn_s_barrier();                                 \
                 __builtin_amdgcn_sched_barrier(0); }

    // prologue: super s0, phase-0 tile staged; B for phase 1 in flight
    {
        const int S0 = g0 + st0;
        LOADA(S0);
        LOADB(2 * S0);
        STOREA_HALF(0, 0);
        STOREB(0);
        LOADB(2 * S0 + 1);
    }
    LBAR();
    int sNrel = st0 + 1; if (sNrel >= NS) sNrel = 0;   // next super to LOADA

    int cur = 0;
#pragma unroll 1
    for (int ph = 0; ph < 2 * NS; ++ph) {
        MFMA_PHASE(cur);                      // tile ph — compute FIRST
        __builtin_amdgcn_sched_barrier(0);
        if (ph + 1 < 2 * NS) {
            if ((ph & 1) == 0) {
                STOREA_HALF(cur ^ 1, 1);      // current super, half 1
                STOREB(cur ^ 1);              // B tile ph+1
                if (ph + 2 < 2 * NS) {
                    const int Sn = g0 + sNrel;
                    LOADA(Sn);                // next super (16 contiguous instrs)
                    LOADB(2 * Sn);            // B tile ph+2
                }
            } else {
                STOREA_HALF(cur ^ 1, 0);      // NEW super, half 0
                STOREB(cur ^ 1);              // B tile ph+1
                if (ph + 2 < 2 * NS) {
                    const int Sn = g0 + sNrel;
                    LOADB(2 * Sn + 1);        // B tile ph+2
                    sNrel = sNrel + 1; if (sNrel >= NS) sNrel = 0;
                }
            }
        }
        LBAR();
        cur ^= 1;
    }

    // Epilogue: 2 rounds (wm groups); transpose via trs -> coalesced stores
    float* outp = Mpart + (size_t)ks * ((size_t)NFW * IN_DIM) + (size_t)m0 * IN_DIM;
#pragma unroll 1
    for (int w = 0; w < 2; ++w) {
        __syncthreads();
        if (wm == w) {
#pragma unroll
            for (int mf = 0; mf < 2; ++mf)
#pragma unroll
                for (int nf = 0; nf < 4; ++nf)
#pragma unroll
                    for (int r = 0; r < 4; ++r)
                        trs[(mf * 16 + l4 * 4 + r) * 132 + wn * 64 + nf * 16 + l15] = acc[mf][nf][r];
        }
        __syncthreads();
#pragma unroll
        for (int q = 0; q < 4; ++q) {
            int idx = q * 256 + t;            // 0..1023 (32 rows x 32 f32x4)
            int rr = idx >> 5, c4 = (idx & 31) << 2;
            f32x4 v = *reinterpret_cast<const f32x4*>(&trs[rr * 132 + c4]);
            *reinterpret_cast<f32x4*>(outp + (size_t)(w * 32 + rr) * IN_DIM + c4) = v;
        }
    }
#undef LOADA
#undef LOADB
#undef STA1
#undef STOREA_HALF
#undef STOREB
#undef MFMA_PHASE
#undef LBAR
}

// ---------------------------------------------------------------------------
// Kernel 1b: reduce 4 partials -> M bf16. 264,192 f32x4 chunks.
// ---------------------------------------------------------------------------
__global__ __launch_bounds__(256) void k_reduce_M(const float* __restrict__ Mpart,
                                                  unsigned short* __restrict__ Mb) {
    const int idx = blockIdx.x * 256 + threadIdx.x;
    f32x4 s = (f32x4){0.f, 0.f, 0.f, 0.f};
#pragma unroll
    for (int ks = 0; ks < KSPLIT; ++ks) {
        f32x4 v = *reinterpret_cast<const f32x4*>(
            Mpart + (size_t)ks * ((size_t)NFW * IN_DIM) + (size_t)idx * 4);
        s.x += v.x; s.y += v.y; s.z += v.z; s.w += v.w;
    }
    uint2 o;
    o.x = f2bf(s.x) | (f2bf(s.y) << 16);
    o.y = f2bf(s.z) | (f2bf(s.w) << 16);
    *reinterpret_cast<uint2*>(Mb + (size_t)idx * 4) = o;
}

// ---------------------------------------------------------------------------
// Kernel 2 (fused U + chains): block = one 64-j slice. Phase 1: 4 waves
// compute U[256 i][64 j] into LDS; Phase 2: wave 0 runs the 64 sigmoid
// chains from LDS, streaming FW to HBM.
// ---------------------------------------------------------------------------
__global__ __launch_bounds__(256) void k_uchains(const float* __restrict__ xs,
                                                 const unsigned short* __restrict__ Mb,
                                                 const float* __restrict__ fw0,
                                                 float* __restrict__ FW) {
    __shared__ float Ulds[256][68];           // +4 pad
    const int t = threadIdx.x, lane = t & 63, wid = t >> 6;
    const int l15 = lane & 15, l4 = (lane >> 4) & 3;
    const int j0 = blockIdx.x * 64;

    bf16x8 bfr[4][4];                         // [kk][nf], static-indexed
#pragma unroll
    for (int kk = 0; kk < 4; ++kk)
#pragma unroll
        for (int nf = 0; nf < 4; ++nf)
            bfr[kk][nf] = *reinterpret_cast<const bf16x8*>(
                Mb + (size_t)(j0 + nf * 16 + l15) * IN_DIM + kk * 32 + l4 * 8);

#pragma unroll 1
    for (int ib = 0; ib < 4; ++ib) {
        const int i0 = wid * 64 + ib * 16;
        f32x4 acc[4];
#pragma unroll
        for (int nf = 0; nf < 4; ++nf) acc[nf] = (f32x4){0.f, 0.f, 0.f, 0.f};
#pragma unroll
        for (int kk = 0; kk < 4; ++kk) {
            const float* xp = xs + (size_t)(i0 + l15) * IN_DIM + kk * 32 + l4 * 8;
            f32x4 x0 = *reinterpret_cast<const f32x4*>(xp);
            f32x4 x1 = *reinterpret_cast<const f32x4*>(xp + 4);
            union { bf16x8 v; unsigned short s[8]; } af;
            af.s[0] = f2bf(x0.x); af.s[1] = f2bf(x0.y);
            af.s[2] = f2bf(x0.z); af.s[3] = f2bf(x0.w);
            af.s[4] = f2bf(x1.x); af.s[5] = f2bf(x1.y);
            af.s[6] = f2bf(x1.z); af.s[7] = f2bf(x1.w);
#pragma unroll
            for (int nf = 0; nf < 4; ++nf)
                acc[nf] = __builtin_amdgcn_mfma_f32_16x16x32_bf16(af.v, bfr[kk][nf], acc[nf], 0, 0, 0);
        }
#pragma unroll
        for (int nf = 0; nf < 4; ++nf)
#pragma unroll
            for (int r = 0; r < 4; ++r)
                Ulds[i0 + l4 * 4 + r][nf * 16 + l15] = acc[nf][r];
    }
    __syncthreads();

    if (wid == 0) {
        const int j = j0 + lane;
        float fw = fw0[j];
        float* fp = FW + j;
#pragma unroll 8
        for (int i = 0; i < BATCH; ++i) {
            float u = Ulds[i][lane];
            float z = 10.0f * (fw + u - 0.5f);
            fw = 1.0f / (1.0f + __expf(-z));
            fp[(size_t)i * NFW] = fw;
        }
    }
}

// ---------------------------------------------------------------------------
// Kernel 4: preds. Block per i: h = relu(fw1 @ xs_i), out[i] = fw2 . h.
// ---------------------------------------------------------------------------
__global__ __launch_bounds__(256) void k_preds(const float* __restrict__ FW,
                                               const float* __restrict__ xs,
                                               float* __restrict__ out) {
    __shared__ float xsh[IN_DIM];
    __shared__ float hsh[HID];
    const int i = blockIdx.x, t = threadIdx.x;
    if (t < 32) {
        f32x4 v = *reinterpret_cast<const f32x4*>(xs + (size_t)i * IN_DIM + t * 4);
        xsh[t*4+0] = v.x; xsh[t*4+1] = v.y; xsh[t*4+2] = v.z; xsh[t*4+3] = v.w;
    }
    __syncthreads();
    const int k = t >> 2, q = t & 3;
    const float* fr = FW + (size_t)i * NFW + k * IN_DIM + q * 32;
    float p = 0.f;
#pragma unroll
    for (int m = 0; m < 8; ++m) {
        f32x4 v = *reinterpret_cast<const f32x4*>(fr + m * 4);
        const int d = q * 32 + m * 4;
        p += v.x * xsh[d] + v.y * xsh[d+1] + v.z * xsh[d+2] + v.w * xsh[d+3];
    }
    p += __shfl_xor(p, 1);
    p += __shfl_xor(p, 2);
    if (q == 0) hsh[k] = fmaxf(p, 0.f);
    __syncthreads();
    if (t < 64) {
        float v = FW[(size_t)i * NFW + IN_DIM * HID + t] * hsh[t];
        v += __shfl_xor(v, 1);  v += __shfl_xor(v, 2);  v += __shfl_xor(v, 4);
        v += __shfl_xor(v, 8);  v += __shfl_xor(v, 16); v += __shfl_xor(v, 32);
        if (t == 0) out[i] = v;
    }
}

// ---------------------------------------------------------------------------
// Workspace layout (~31.7 MiB):
//   W1T  bf16 :  4,227,072 B @ 0
//   Mpart f32 : 16,908,288 B @  4,227,072   (4 x 8256 x 128)
//   Mb   bf16 :  2,113,536 B @ 21,135,360
//   FW   f32  :  8,454,144 B @ 23,248,896
// ---------------------------------------------------------------------------
extern "C" void kernel_launch(void* const* d_in, const int* in_sizes, int n_in,
                              void* d_out, int out_size, void* d_ws, size_t ws_size,
                              hipStream_t stream) {
    const float* x   = (const float*)d_in[0];   // (256,1,128)
    const float* W1  = (const float*)d_in[1];   // (16512,128)
    const float* W2  = (const float*)d_in[2];   // (8256,16512)
    const float* fw0 = (const float*)d_in[3];   // (8256,)
    float* out = (float*)d_out;                 // 256 f32

    char* ws = (char*)d_ws;
    unsigned short* W1T   = (unsigned short*)(ws);
    float*          Mpart = (float*)(ws + 4227072);
    unsigned short* Mb    = (unsigned short*)(ws + 21135360);
    float*          FW    = (float*)(ws + 23248896);

    hipLaunchKernelGGL(k_prep_w1t, dim3(258),    dim3(256), 0, stream, W1, W1T);
    hipLaunchKernelGGL(k_gemm_M,   dim3(GRID_M), dim3(256), 0, stream, W2, W1T, Mpart);
    hipLaunchKernelGGL(k_reduce_M, dim3(1032),   dim3(256), 0, stream, Mpart, Mb);
    hipLaunchKernelGGL(k_uchains,  dim3(129),    dim3(256), 0, stream, x, Mb, fw0, FW);
    hipLaunchKernelGGL(k_preds,    dim3(256),    dim3(256), 0, stream, FW, x, out);
}

// Round 16
// 165.470 us; speedup vs baseline: 1.2759x; 1.2759x over previous
//
#include <hip/hip_runtime.h>
#include <hip/hip_bf16.h>

// Problem constants
#define IN_DIM 128
#define HID    64
#define NFW    8256     // IN*HID + HID
#define BATCH  256
#define K2     16512    // 2*NFW
#define BM     64       // rows per m-block
#define NMB    129      // 8256/64
#define KSPLIT 6
#define NT_PER 43       // k-tiles (of 64) per split; 6*43 = 258
#define GRID_M 774      // NMB * KSPLIT

typedef float f32x4 __attribute__((ext_vector_type(4)));
typedef short bf16x8 __attribute__((ext_vector_type(8)));

__device__ __forceinline__ unsigned int f2bf(float f) {
    union { float f; unsigned int u; } v; v.f = f;
    return (v.u + 0x7FFFu + ((v.u >> 16) & 1u)) >> 16;   // RNE f32->bf16 (bits)
}

__device__ __forceinline__ bf16x8 pack8(f32x4 a, f32x4 b) {
    union { bf16x8 v; __hip_bfloat162 h[4]; } u;
    u.h[0] = __float22bfloat162_rn(float2{a.x, a.y});
    u.h[1] = __float22bfloat162_rn(float2{a.z, a.w});
    u.h[2] = __float22bfloat162_rn(float2{b.x, b.y});
    u.h[3] = __float22bfloat162_rn(float2{b.z, b.w});
    return u.v;
}

// global -> LDS direct DMA, 16B per lane. dst is WAVE-UNIFORM base (HW adds
// lane*16); src is PER-LANE (pre-swizzled global address = swizzled LDS).
#define GLL16(SRC, DST)                                                        \
    __builtin_amdgcn_global_load_lds(                                          \
        (const __attribute__((address_space(1))) unsigned int*)(SRC),          \
        (__attribute__((address_space(3))) unsigned int*)(DST), 16, 0, 0)

// ---------------------------------------------------------------------------
// Kernel 0: W1 (16512x128 f32) -> W1T tiled bf16. Tile kt: [128 n][64 kl].
// ---------------------------------------------------------------------------
__global__ __launch_bounds__(256) void k_prep_w1t(const float* __restrict__ W1,
                                                  unsigned short* __restrict__ W1T) {
    __shared__ float tile[64][IN_DIM + 1];
    const int kt = blockIdx.x;               // 0..257
    const int t  = threadIdx.x;
    const float* src = W1 + (size_t)kt * 64 * IN_DIM;
#pragma unroll
    for (int p = 0; p < 8; ++p) {
        int c4 = p * 256 + t;
        int e = c4 * 4;
        int row = e >> 7, col = e & 127;
        f32x4 v = *reinterpret_cast<const f32x4*>(src + row * IN_DIM + col);
        tile[row][col+0] = v.x; tile[row][col+1] = v.y;
        tile[row][col+2] = v.z; tile[row][col+3] = v.w;
    }
    __syncthreads();
    unsigned short* dst = W1T + (size_t)kt * (IN_DIM * 64);
#pragma unroll
    for (int it = 0; it < 4; ++it) {
        int c = it * 256 + t;
        int n = c >> 3, kl0 = (c & 7) * 8;
        uint4 w;
        w.x = f2bf(tile[kl0+0][n]) | (f2bf(tile[kl0+1][n]) << 16);
        w.y = f2bf(tile[kl0+2][n]) | (f2bf(tile[kl0+3][n]) << 16);
        w.z = f2bf(tile[kl0+4][n]) | (f2bf(tile[kl0+5][n]) << 16);
        w.w = f2bf(tile[kl0+6][n]) | (f2bf(tile[kl0+7][n]) << 16);
        *reinterpret_cast<uint4*>(dst + c * 8) = w;
    }
}

// ---------------------------------------------------------------------------
// Kernel 1: split-K GEMM staged via __builtin_amdgcn_global_load_lds (the
// one technique never tried in R3-R15; guide Common-mistake #1). Per wave
// per tile: 8 GLL issue-instructions — no VGPR round-trip, no cvt-at-stage,
// no ds_write chain. A kept as f32 in LDS (16KB/tile); converted to bf16 at
// frag-read via v_cvt_pk (hidden under HBM pace). Swizzle done by
// PRE-SWIZZLING the per-lane GLOBAL source (LDS stays linear, rule 21/m173);
// frag reads apply the same XOR -> conflict-free as R13. 64KB LDS -> 2
// blocks/CU. __syncthreads per iter = m97's proven drain structure.
// Keeps: XCD k-grouping, k-stagger, MFMA layout, transposed epilogue.
// ---------------------------------------------------------------------------
__global__ __launch_bounds__(256) void k_gemm_M(const float* __restrict__ W2,
                                                const unsigned short* __restrict__ W1T,
                                                float* __restrict__ Mpart) {
    __shared__ __align__(16) unsigned char smem[65536];  // A f32: 2x16K @0; B bf16: 2x16K @32K
    float* trs = reinterpret_cast<float*>(smem);         // [32][132] epilogue alias

    const int t = threadIdx.x;
    const int lane = t & 63, wid = t >> 6;
    const int wm = wid >> 1, wn = wid & 1;    // wave grid 2m x 2n
    const int l15 = lane & 15, l4 = (lane >> 4) & 3;

    // bijective blockIdx -> (ks, mb); one XCD stays on one k-split (688KB
    // W1T slice L2-resident). 774 = 6*97 + 2*96.
    const int b = blockIdx.x;
    const int xcd = b & 7, slot = b >> 3;
    const int p = (xcd < 6) ? (xcd * 97 + slot) : (582 + (xcd - 6) * 96 + slot);
    const int ks = p / NMB, mb = p % NMB;

    const int m0 = mb * BM;
    const int g0 = ks * NT_PER;
    const int kt0 = (p * 7) % NT_PER;         // K-phase stagger (fp32 acc: safe)

    // ---- per-thread GLL source pointers (loop-invariant; += tile stride) ----
    // A: chunk c = wid*4+j covers rows 4c..4c+3 (1KB LDS each). Lane l ->
    // row rl = 4c + (l>>4), LDS byte (l&15)*16; source column PRE-SWIZZLED.
    const int ca0 = wid * 4;
    const int rl0 = 4 * (ca0 + 0) + (lane >> 4);
    const int rl1 = 4 * (ca0 + 1) + (lane >> 4);
    const int rl2 = 4 * (ca0 + 2) + (lane >> 4);
    const int rl3 = 4 * (ca0 + 3) + (lane >> 4);
    const int acb = (lane & 15) * 16;         // LDS byte col within 256B row
    const float* aS0 = W2 + (size_t)(m0 + rl0) * K2 + (size_t)g0 * 64 + ((acb ^ ((rl0 & 7) << 4)) >> 2);
    const float* aS1 = W2 + (size_t)(m0 + rl1) * K2 + (size_t)g0 * 64 + ((acb ^ ((rl1 & 7) << 4)) >> 2);
    const float* aS2 = W2 + (size_t)(m0 + rl2) * K2 + (size_t)g0 * 64 + ((acb ^ ((rl2 & 7) << 4)) >> 2);
    const float* aS3 = W2 + (size_t)(m0 + rl3) * K2 + (size_t)g0 * 64 + ((acb ^ ((rl3 & 7) << 4)) >> 2);
    // B: chunk c covers rows 8c..8c+7 (128B each). Lane l -> row rb = 8c +
    // (l>>3), LDS byte (l&7)*16; source pre-swizzled. W1T tile: [128][64]bf16.
    const int rb0 = 8 * (ca0 + 0) + (lane >> 3);
    const int rb1 = 8 * (ca0 + 1) + (lane >> 3);
    const int rb2 = 8 * (ca0 + 2) + (lane >> 3);
    const int rb3 = 8 * (ca0 + 3) + (lane >> 3);
    const int bcb = (lane & 7) * 16;
    const unsigned short* bS0 = W1T + (size_t)g0 * 8192 + rb0 * 64 + ((bcb ^ ((rb0 & 7) << 4)) >> 1);
    const unsigned short* bS1 = W1T + (size_t)g0 * 8192 + rb1 * 64 + ((bcb ^ ((rb1 & 7) << 4)) >> 1);
    const unsigned short* bS2 = W1T + (size_t)g0 * 8192 + rb2 * 64 + ((bcb ^ ((rb2 & 7) << 4)) >> 1);
    const unsigned short* bS3 = W1T + (size_t)g0 * 8192 + rb3 * 64 + ((bcb ^ ((rb3 & 7) << 4)) >> 1);
    // wave-uniform LDS dest bases (HW adds lane*16)
    const int aD = ca0 * 1024;                // chunk j: aD + j*1024

    f32x4 acc[2][4];
#pragma unroll
    for (int mf = 0; mf < 2; ++mf)
#pragma unroll
        for (int nf = 0; nf < 4; ++nf)
            acc[mf][nf] = (f32x4){0.f, 0.f, 0.f, 0.f};

#define ISSUE_AB(BUF, KT) {                                                    \
    unsigned char* _ab = smem + (BUF) * 16384;                                 \
    unsigned char* _bb = smem + 32768 + (BUF) * 16384;                         \
    const size_t _ao = (size_t)(KT) * 64;                                      \
    const size_t _bo = (size_t)(KT) * 8192;                                    \
    GLL16(aS0 + _ao, _ab + aD);                                                \
    GLL16(aS1 + _ao, _ab + aD + 1024);                                         \
    GLL16(aS2 + _ao, _ab + aD + 2048);                                         \
    GLL16(aS3 + _ao, _ab + aD + 3072);                                         \
    GLL16(bS0 + _bo, _bb + aD);                                                \
    GLL16(bS1 + _bo, _bb + aD + 1024);                                         \
    GLL16(bS2 + _bo, _bb + aD + 2048);                                         \
    GLL16(bS3 + _bo, _bb + aD + 3072);                                         \
}

#define MFMA_PHASE(BUF) {                                                      \
    const unsigned char* _Ash = smem + (BUF) * 16384;                          \
    const unsigned char* _Bsh = smem + 32768 + (BUF) * 16384;                  \
    _Pragma("unroll")                                                          \
    for (int kk = 0; kk < 2; ++kk) {                                           \
        const int _ar0 = wm * 32 + l15;                                        \
        const int _ar1 = wm * 32 + 16 + l15;                                   \
        const int _pb  = kk * 128 + l4 * 32;                                   \
        const int _s0  = (_ar0 & 7) << 4;                                      \
        const int _s1  = (_ar1 & 7) << 4;                                      \
        f32x4 _x0 = *reinterpret_cast<const f32x4*>(&_Ash[_ar0 * 256 + ((_pb)      ^ _s0)]); \
        f32x4 _x1 = *reinterpret_cast<const f32x4*>(&_Ash[_ar0 * 256 + ((_pb + 16) ^ _s0)]); \
        f32x4 _y0 = *reinterpret_cast<const f32x4*>(&_Ash[_ar1 * 256 + ((_pb)      ^ _s1)]); \
        f32x4 _y1 = *reinterpret_cast<const f32x4*>(&_Ash[_ar1 * 256 + ((_pb + 16) ^ _s1)]); \
        bf16x8 af0 = pack8(_x0, _x1);                                          \
        bf16x8 af1 = pack8(_y0, _y1);                                          \
        const int _fsw = (l15 & 7) << 4;                                       \
        const int _fc  = (kk * 64 + l4 * 16) ^ _fsw;                           \
        bf16x8 bf0 = *reinterpret_cast<const bf16x8*>(&_Bsh[(wn * 64 +  0 + l15) * 128 + _fc]); \
        bf16x8 bf1 = *reinterpret_cast<const bf16x8*>(&_Bsh[(wn * 64 + 16 + l15) * 128 + _fc]); \
        bf16x8 bf2 = *reinterpret_cast<const bf16x8*>(&_Bsh[(wn * 64 + 32 + l15) * 128 + _fc]); \
        bf16x8 bf3 = *reinterpret_cast<const bf16x8*>(&_Bsh[(wn * 64 + 48 + l15) * 128 + _fc]); \
        acc[0][0] = __builtin_amdgcn_mfma_f32_16x16x32_bf16(af0, bf0, acc[0][0], 0, 0, 0); \
        acc[0][1] = __builtin_amdgcn_mfma_f32_16x16x32_bf16(af0, bf1, acc[0][1], 0, 0, 0); \
        acc[0][2] = __builtin_amdgcn_mfma_f32_16x16x32_bf16(af0, bf2, acc[0][2], 0, 0, 0); \
        acc[0][3] = __builtin_amdgcn_mfma_f32_16x16x32_bf16(af0, bf3, acc[0][3], 0, 0, 0); \
        acc[1][0] = __builtin_amdgcn_mfma_f32_16x16x32_bf16(af1, bf0, acc[1][0], 0, 0, 0); \
        acc[1][1] = __builtin_amdgcn_mfma_f32_16x16x32_bf16(af1, bf1, acc[1][1], 0, 0, 0); \
        acc[1][2] = __builtin_amdgcn_mfma_f32_16x16x32_bf16(af1, bf2, acc[1][2], 0, 0, 0); \
        acc[1][3] = __builtin_amdgcn_mfma_f32_16x16x32_bf16(af1, bf3, acc[1][3], 0, 0, 0); \
    } }

    // prologue: DMA tile kt0 into buf0, drain
    int tcur = kt0;
    ISSUE_AB(0, tcur);
    __syncthreads();

    int cur = 0;
#pragma unroll 1
    for (int i = 0; i < NT_PER; ++i) {
        if (i + 1 < NT_PER) {
            int tn = tcur + 1; if (tn >= NT_PER) tn = 0;
            ISSUE_AB(cur ^ 1, tn);            // DMA tile i+1 (lands during MFMA)
            tcur = tn;
        }
        MFMA_PHASE(cur);                      // tile i
        __syncthreads();                      // vmcnt+lgkm drain + barrier
        cur ^= 1;
    }

    // Epilogue: 2 rounds (wm groups); transpose via trs -> coalesced stores
    float* outp = Mpart + (size_t)ks * ((size_t)NFW * IN_DIM) + (size_t)m0 * IN_DIM;
#pragma unroll 1
    for (int w = 0; w < 2; ++w) {
        __syncthreads();
        if (wm == w) {
#pragma unroll
            for (int mf = 0; mf < 2; ++mf)
#pragma unroll
                for (int nf = 0; nf < 4; ++nf)
#pragma unroll
                    for (int r = 0; r < 4; ++r)
                        trs[(mf * 16 + l4 * 4 + r) * 132 + wn * 64 + nf * 16 + l15] = acc[mf][nf][r];
        }
        __syncthreads();
#pragma unroll
        for (int q = 0; q < 4; ++q) {
            int idx = q * 256 + t;            // 0..1023 (32 rows x 32 f32x4)
            int rr = idx >> 5, c4 = (idx & 31) << 2;
            f32x4 v = *reinterpret_cast<const f32x4*>(&trs[rr * 132 + c4]);
            *reinterpret_cast<f32x4*>(outp + (size_t)(w * 32 + rr) * IN_DIM + c4) = v;
        }
    }
#undef ISSUE_AB
#undef MFMA_PHASE
}

// ---------------------------------------------------------------------------
// Kernel 1b: reduce 6 partials -> M bf16. 264,192 f32x4 chunks.
// ---------------------------------------------------------------------------
__global__ __launch_bounds__(256) void k_reduce_M(const float* __restrict__ Mpart,
                                                  unsigned short* __restrict__ Mb) {
    const int idx = blockIdx.x * 256 + threadIdx.x;
    f32x4 s = (f32x4){0.f, 0.f, 0.f, 0.f};
#pragma unroll
    for (int ks = 0; ks < KSPLIT; ++ks) {
        f32x4 v = *reinterpret_cast<const f32x4*>(
            Mpart + (size_t)ks * ((size_t)NFW * IN_DIM) + (size_t)idx * 4);
        s.x += v.x; s.y += v.y; s.z += v.z; s.w += v.w;
    }
    uint2 o;
    o.x = f2bf(s.x) | (f2bf(s.y) << 16);
    o.y = f2bf(s.z) | (f2bf(s.w) << 16);
    *reinterpret_cast<uint2*>(Mb + (size_t)idx * 4) = o;
}

// ---------------------------------------------------------------------------
// Kernel 2 (fused U + chains): block = one 64-j slice. Phase 1: 4 waves
// compute U[256 i][64 j] into LDS; Phase 2: wave 0 runs the 64 sigmoid
// chains from LDS, streaming FW to HBM.
// ---------------------------------------------------------------------------
__global__ __launch_bounds__(256) void k_uchains(const float* __restrict__ xs,
                                                 const unsigned short* __restrict__ Mb,
                                                 const float* __restrict__ fw0,
                                                 float* __restrict__ FW) {
    __shared__ float Ulds[256][68];           // +4 pad
    const int t = threadIdx.x, lane = t & 63, wid = t >> 6;
    const int l15 = lane & 15, l4 = (lane >> 4) & 3;
    const int j0 = blockIdx.x * 64;

    bf16x8 bfr[4][4];                         // [kk][nf], static-indexed
#pragma unroll
    for (int kk = 0; kk < 4; ++kk)
#pragma unroll
        for (int nf = 0; nf < 4; ++nf)
            bfr[kk][nf] = *reinterpret_cast<const bf16x8*>(
                Mb + (size_t)(j0 + nf * 16 + l15) * IN_DIM + kk * 32 + l4 * 8);

#pragma unroll 1
    for (int ib = 0; ib < 4; ++ib) {
        const int i0 = wid * 64 + ib * 16;
        f32x4 acc[4];
#pragma unroll
        for (int nf = 0; nf < 4; ++nf) acc[nf] = (f32x4){0.f, 0.f, 0.f, 0.f};
#pragma unroll
        for (int kk = 0; kk < 4; ++kk) {
            const float* xp = xs + (size_t)(i0 + l15) * IN_DIM + kk * 32 + l4 * 8;
            f32x4 x0 = *reinterpret_cast<const f32x4*>(xp);
            f32x4 x1 = *reinterpret_cast<const f32x4*>(xp + 4);
            union { bf16x8 v; unsigned short s[8]; } af;
            af.s[0] = f2bf(x0.x); af.s[1] = f2bf(x0.y);
            af.s[2] = f2bf(x0.z); af.s[3] = f2bf(x0.w);
            af.s[4] = f2bf(x1.x); af.s[5] = f2bf(x1.y);
            af.s[6] = f2bf(x1.z); af.s[7] = f2bf(x1.w);
#pragma unroll
            for (int nf = 0; nf < 4; ++nf)
                acc[nf] = __builtin_amdgcn_mfma_f32_16x16x32_bf16(af.v, bfr[kk][nf], acc[nf], 0, 0, 0);
        }
#pragma unroll
        for (int nf = 0; nf < 4; ++nf)
#pragma unroll
            for (int r = 0; r < 4; ++r)
                Ulds[i0 + l4 * 4 + r][nf * 16 + l15] = acc[nf][r];
    }
    __syncthreads();

    if (wid == 0) {
        const int j = j0 + lane;
        float fw = fw0[j];
        float* fp = FW + j;
#pragma unroll 8
        for (int i = 0; i < BATCH; ++i) {
            float u = Ulds[i][lane];
            float z = 10.0f * (fw + u - 0.5f);
            fw = 1.0f / (1.0f + __expf(-z));
            fp[(size_t)i * NFW] = fw;
        }
    }
}

// ---------------------------------------------------------------------------
// Kernel 4: preds. Block per i: h = relu(fw1 @ xs_i), out[i] = fw2 . h.
// ---------------------------------------------------------------------------
__global__ __launch_bounds__(256) void k_preds(const float* __restrict__ FW,
                                               const float* __restrict__ xs,
                                               float* __restrict__ out) {
    __shared__ float xsh[IN_DIM];
    __shared__ float hsh[HID];
    const int i = blockIdx.x, t = threadIdx.x;
    if (t < 32) {
        f32x4 v = *reinterpret_cast<const f32x4*>(xs + (size_t)i * IN_DIM + t * 4);
        xsh[t*4+0] = v.x; xsh[t*4+1] = v.y; xsh[t*4+2] = v.z; xsh[t*4+3] = v.w;
    }
    __syncthreads();
    const int k = t >> 2, q = t & 3;
    const float* fr = FW + (size_t)i * NFW + k * IN_DIM + q * 32;
    float p = 0.f;
#pragma unroll
    for (int m = 0; m < 8; ++m) {
        f32x4 v = *reinterpret_cast<const f32x4*>(fr + m * 4);
        const int d = q * 32 + m * 4;
        p += v.x * xsh[d] + v.y * xsh[d+1] + v.z * xsh[d+2] + v.w * xsh[d+3];
    }
    p += __shfl_xor(p, 1);
    p += __shfl_xor(p, 2);
    if (q == 0) hsh[k] = fmaxf(p, 0.f);
    __syncthreads();
    if (t < 64) {
        float v = FW[(size_t)i * NFW + IN_DIM * HID + t] * hsh[t];
        v += __shfl_xor(v, 1);  v += __shfl_xor(v, 2);  v += __shfl_xor(v, 4);
        v += __shfl_xor(v, 8);  v += __shfl_xor(v, 16); v += __shfl_xor(v, 32);
        if (t == 0) out[i] = v;
    }
}

// ---------------------------------------------------------------------------
// Workspace layout (~40.2 MiB):
//   W1T  bf16 :  4,227,072 B @ 0
//   Mpart f32 : 25,362,432 B @  4,227,072   (6 x 8256 x 128)
//   Mb   bf16 :  2,113,536 B @ 29,589,504
//   FW   f32  :  8,454,144 B @ 31,703,040
// ---------------------------------------------------------------------------
extern "C" void kernel_launch(void* const* d_in, const int* in_sizes, int n_in,
                              void* d_out, int out_size, void* d_ws, size_t ws_size,
                              hipStream_t stream) {
    const float* x   = (const float*)d_in[0];   // (256,1,128)
    const float* W1  = (const float*)d_in[1];   // (16512,128)
    const float* W2  = (const float*)d_in[2];   // (8256,16512)
    const float* fw0 = (const float*)d_in[3];   // (8256,)
    float* out = (float*)d_out;                 // 256 f32

    char* ws = (char*)d_ws;
    unsigned short* W1T   = (unsigned short*)(ws);
    float*          Mpart = (float*)(ws + 4227072);
    unsigned short* Mb    = (unsigned short*)(ws + 29589504);
    float*          FW    = (float*)(ws + 31703040);

    hipLaunchKernelGGL(k_prep_w1t, dim3(258),    dim3(256), 0, stream, W1, W1T);
    hipLaunchKernelGGL(k_gemm_M,   dim3(GRID_M), dim3(256), 0, stream, W2, W1T, Mpart);
    hipLaunchKernelGGL(k_reduce_M, dim3(1032),   dim3(256), 0, stream, Mpart, Mb);
    hipLaunchKernelGGL(k_uchains,  dim3(129),    dim3(256), 0, stream, x, Mb, fw0, FW);
    hipLaunchKernelGGL(k_preds,    dim3(256),    dim3(256), 0, stream, FW, x, out);
}